// Round 1
// baseline (150.203 us; speedup 1.0000x reference)
//
#include <hip/hip_runtime.h>
#include <stdint.h>

#define HH 512
#define WW 512
#define ALPHA_MIN_C (1.0f/255.0f)
#define ALPHA_MAX_C 0.99f
#define BLUR_C 0.3f
#define TERM_EPS 1.0e-4f

// ---------------- Kernel 1: distributed stable rank computation ----------------
// key = (float_bits(depth) << 32) | index  (depths >= 0 so bit order == value order)
// rank[g] = #{ j : key[j] < key[g] }  -> exact sorted position (stable, unique keys)
// Grid: (N/256 g-blocks) x (N/JCHUNK j-slices), 256 threads.
#define JCHUNK 1024
__global__ __launch_bounds__(256) void rank_kernel(const float* __restrict__ depths,
                                                   int N, int* __restrict__ rank) {
    __shared__ uint64_t sk[JCHUNK];
    const int tid = threadIdx.x;
    const int ngb = N >> 8;                 // N/256
    const int gb = blockIdx.x % ngb;
    const int jb = blockIdx.x / ngb;
    const int j0 = jb * JCHUNK;
    for (int i = tid; i < JCHUNK; i += 256) {
        int j = j0 + i;
        uint32_t bits = __float_as_uint(depths[j]);
        sk[i] = ((uint64_t)bits << 32) | (uint32_t)j;
    }
    __syncthreads();
    const int g = gb * 256 + tid;
    const uint32_t mb = __float_as_uint(depths[g]);
    const uint64_t mykey = ((uint64_t)mb << 32) | (uint32_t)g;
    int cnt = 0;
#pragma unroll 8
    for (int i = 0; i < JCHUNK; ++i)
        cnt += (sk[i] < mykey) ? 1 : 0;
    atomicAdd(&rank[g], cnt);
}

// ---------------- Kernel 2: per-gaussian prep, scattered into sorted order ----
__global__ __launch_bounds__(256) void prep_kernel(
    const float* __restrict__ means, const float* __restrict__ colors,
    const float* __restrict__ ops, const float* __restrict__ scales,
    const float* __restrict__ rots, const int* __restrict__ rank, int N,
    float4* __restrict__ pA, float4* __restrict__ pB,
    float* __restrict__ pC, float* __restrict__ pR) {
    int g = blockIdx.x * 256 + threadIdx.x;
    if (g >= N) return;
    int pos = rank[g];
    float mx = means[2*g], my = means[2*g+1];
    float th = rots[g];
    float c = cosf(th), si = sinf(th);
    float sx = scales[2*g], sy = scales[2*g+1];
    float sx2 = sx*sx, sy2 = sy*sy;
    float A  = c*c*sx2 + si*si*sy2;
    float Cc = si*si*sx2 + c*c*sy2;
    float B  = c*si*(sx2 - sy2);
    float det = A*Cc - B*B;
    float A2 = A + BLUR_C, C2 = Cc + BLUR_C;
    float det2 = A2*C2 - B*B;
    float op = ops[g] * sqrtf(fmaxf(det/det2, 0.0f));
    float invd = 1.0f/det2;
    float ia = C2*invd, ib = -B*invd, ic = A2*invd;
    // conservative cull radius^2: alpha < ALPHA_MIN guaranteed beyond it
    float mid = 0.5f*(A2+C2);
    float lam = mid + sqrtf(fmaxf(mid*mid - det2, 0.0f));   // max eigenvalue of dilated cov
    float r2;
    if (op < ALPHA_MIN_C) {
        r2 = -1.0f;                                         // never visible
    } else {
        float t = __logf(op * 255.0f);                      // ln(op/ALPHA_MIN)
        r2 = fmaxf(2.0f * lam * t, 0.0f) * 1.0001f + 0.25f; // margin for fp rounding
    }
    pA[pos] = make_float4(mx, my, ia, ib);
    pB[pos] = make_float4(ic, op, colors[3*g], colors[3*g+1]);
    pC[pos] = colors[3*g+2];
    pR[pos] = r2;
}

// ---------------- Kernel 3: tiled blend, 1 block per 16x16 tile ---------------
__global__ __launch_bounds__(256) void blend_kernel(
    const float4* __restrict__ pA, const float4* __restrict__ pB,
    const float* __restrict__ pC, const float* __restrict__ pR,
    const float* __restrict__ bg, int N, float* __restrict__ out) {
    __shared__ float4 sA[256];
    __shared__ float4 sB[256];
    __shared__ float  sC[256];
    __shared__ int    wcnt[4];
    const int tid = threadIdx.x;
    const int tileX = blockIdx.x & 31, tileY = blockIdx.x >> 5;
    const int px = tileX*16 + (tid & 15);
    const int py = tileY*16 + (tid >> 4);
    const float fx = px + 0.5f, fy = py + 0.5f;
    const float x0 = tileX*16 + 0.5f, x1 = tileX*16 + 15.5f;
    const float y0 = tileY*16 + 0.5f, y1 = tileY*16 + 15.5f;
    const int lane = tid & 63, wid = tid >> 6;
    float T = 1.0f, accR = 0.0f, accG = 0.0f, accB = 0.0f;

    for (int base = 0; base < N; base += 256) {
        const int g = base + tid;
        float4 a = pA[g];
        float4 b = pB[g];
        float cb = pC[g];
        float r2 = pR[g];
        // nearest point of tile's pixel-center rectangle to the mean
        float nx = fminf(fmaxf(a.x, x0), x1) - a.x;
        float ny = fminf(fmaxf(a.y, y0), y1) - a.y;
        bool flag = (nx*nx + ny*ny) <= r2;
        uint64_t mask = __ballot(flag);
        if (lane == 0) wcnt[wid] = __popcll(mask);
        __syncthreads();
        int off = __popcll(mask & ((1ull << lane) - 1ull));
        for (int w2 = 0; w2 < wid; ++w2) off += wcnt[w2];
        const int M = wcnt[0] + wcnt[1] + wcnt[2] + wcnt[3];
        if (flag) { sA[off] = a; sB[off] = b; sC[off] = cb; }
        __syncthreads();
        // sequential front-to-back blend over compacted (order-preserving) list
        for (int i = 0; i < M; ++i) {
            float4 ga = sA[i];
            float4 gb = sB[i];
            float dx = fx - ga.x, dy = fy - ga.y;
            float power = -0.5f*(ga.z*dx*dx + gb.x*dy*dy) - ga.w*dx*dy;
            float alpha = fminf(ALPHA_MAX_C, gb.y * __expf(power));
            if (alpha >= ALPHA_MIN_C) {
                float w = alpha * T;
                accR += gb.z * w;
                accG += gb.w * w;
                accB += sC[i] * w;
                T *= (1.0f - alpha);
            }
        }
        // barrier doubles as LDS reuse guard; exact-enough early exit
        if (__syncthreads_and(T < TERM_EPS)) break;
    }
    const int pix = py*WW + px;
    out[pix]             = accR + bg[0]*T;
    out[pix +   HH*WW]   = accG + bg[1]*T;
    out[pix + 2*HH*WW]   = accB + bg[2]*T;
}

extern "C" void kernel_launch(void* const* d_in, const int* in_sizes, int n_in,
                              void* d_out, int out_size, void* d_ws, size_t ws_size,
                              hipStream_t stream) {
    const float* means   = (const float*)d_in[0];
    const float* colors  = (const float*)d_in[1];
    const float* ops     = (const float*)d_in[2];
    const float* scales  = (const float*)d_in[3];
    const float* rots    = (const float*)d_in[4];
    const float* depths  = (const float*)d_in[5];
    const float* bg      = (const float*)d_in[6];
    const int N = in_sizes[0] / 2;           // 8192

    char* ws = (char*)d_ws;
    float4* pA  = (float4*)(ws);                         // N*16 B
    float4* pB  = (float4*)(ws + (size_t)N*16);          // N*16 B
    float*  pC  = (float*)(ws + (size_t)N*32);           // N*4 B
    float*  pR  = (float*)(ws + (size_t)N*36);           // N*4 B
    int*    rank= (int*)  (ws + (size_t)N*40);           // N*4 B

    hipMemsetAsync(rank, 0, (size_t)N*4, stream);

    const int ngb = N / 256;
    const int njb = N / JCHUNK;
    rank_kernel<<<dim3(ngb*njb), dim3(256), 0, stream>>>(depths, N, rank);
    prep_kernel<<<dim3((N+255)/256), dim3(256), 0, stream>>>(
        means, colors, ops, scales, rots, rank, N, pA, pB, pC, pR);
    blend_kernel<<<dim3((WW/16)*(HH/16)), dim3(256), 0, stream>>>(
        pA, pB, pC, pR, bg, N, (float*)d_out);
}